// Round 3
// baseline (43.644 us; speedup 1.0000x reference)
//
#include <hip/hip_runtime.h>
#include <hip/hip_fp16.h>
#include <math.h>

#define HH 8
#define WW 32
#define HW 256
#define NN 20
#define FF 128
#define LL 1024
#define AA 360
#define CO 64
#define KK 5120          // NN*HW
#define KS 8             // K splits
#define KC 640           // K per split
#define BM 32            // rows per block in kC
#define BK 64            // K per LDS step

// workspace offsets (in floats)
#define OFF_LPANO      (AA*HW)
#define OFF_OV(B)      (OFF_LPANO + (B)*NN*HW)
#define OFF_SCAL(B)    (OFF_OV(B) + (B)*LL*2)
#define OFF_D(B)       (OFF_SCAL(B) + 8)
#define OFF_IDX(B)     (OFF_D(B) + (B)*LL*NN)
#define OFF_BASE2(B)   (OFF_IDX(B) + (B)*LL*NN)
#define OFF_MX(B)      (OFF_BASE2(B) + (B)*LL*NN)
#define OFF_INV(B)     (OFF_MX(B) + (B)*LL)
#define OFF_BT(B)      (((OFF_INV(B) + (B)*LL + 7)/8)*8)   // f16 Bt [B][128][5120]
#define OFF_CP(B)      (OFF_BT(B) + (B)*FF*KK/2)           // f32 partials [KS][B*LL][128]

typedef __attribute__((ext_vector_type(8))) _Float16 f16x8;
typedef __attribute__((ext_vector_type(4))) _Float16 f16x4;
typedef __attribute__((ext_vector_type(4))) float f32x4;

// ---------------------------------------------------------------------------
// kA: fused prologue — [0,g1): tables/stats/scalars; [g1,g1+gGeo): geometry;
//     [g1+gGeo, ...): feats -> Bt f16 permute. All independent.
// ---------------------------------------------------------------------------
__global__ __launch_bounds__(256)
void kA_pre(const float* __restrict__ bbox, const float* __restrict__ locs,
            const float* __restrict__ rays, const float* __restrict__ feats,
            const float* __restrict__ overhead,
            const float* __restrict__ W1, const float* __restrict__ b1,
            const float* __restrict__ W2, const float* __restrict__ b2,
            const float* __restrict__ Wf, const float* __restrict__ bfp,
            float* __restrict__ ws, int B)
{
    const int bid = blockIdx.x, tid = threadIdx.x;
    const int g1 = AA + B*NN + B*4 + 1;
    const int gGeo = (B*LL*NN + 255)/256;

    if (bid < g1) {
        const float wf0 = Wf[0], wf1 = Wf[1];

        if (bid < AA) {                       // ---- Lray for angle bid
            __shared__ float s[3*HW];
            for (int c = 0; c < 3; ++c) s[c*HW + tid] = rays[(bid*3 + c)*HW + tid];
            __syncthreads();
            const int h = tid >> 5, w = tid & 31;
            float c1 = 0.f, c2 = 0.f;
            #pragma unroll
            for (int c = 0; c < 3; ++c) {
                #pragma unroll
                for (int ky = 0; ky < 3; ++ky)
                    #pragma unroll
                    for (int kx = 0; kx < 3; ++kx)
                        c1 += W1[(1+c)*9 + ky*3 + kx] *
                              s[c*HW + (((h+ky+7)&7)<<5) + ((w+kx+31)&31)];
                #pragma unroll
                for (int ky = 0; ky < 5; ++ky)
                    #pragma unroll
                    for (int kx = 0; kx < 5; ++kx)
                        c2 += W2[(1+c)*25 + ky*5 + kx] *
                              s[c*HW + (((h+ky+6)&7)<<5) + ((w+kx+30)&31)];
            }
            ws[bid*HW + tid] = wf0*c1 + wf1*c2;
            return;
        }

        const int pb = bid - AA;
        if (pb < B*NN) {                      // ---- pano stats + conv -> Lpano
            __shared__ float p[2*HW];
            const float* fp = feats + (size_t)pb * FF * HW + tid;
            float mx = -INFINITY; double sm = 0.0;
            for (int f = 0; f < FF; ++f) {
                float v = fp[(size_t)f * HW];
                mx = fmaxf(mx, v); sm += (double)v;
            }
            p[tid]      = mx;
            p[HW + tid] = (float)(sm / 128.0);
            __syncthreads();
            const int h = tid >> 5, w = tid & 31;
            float c1 = 0.f, c2 = 0.f;
            #pragma unroll
            for (int c = 0; c < 2; ++c) {
                #pragma unroll
                for (int ky = 0; ky < 3; ++ky)
                    #pragma unroll
                    for (int kx = 0; kx < 3; ++kx)
                        c1 += W1[(4+c)*9 + ky*3 + kx] *
                              p[c*HW + (((h+ky+7)&7)<<5) + ((w+kx+31)&31)];
                #pragma unroll
                for (int ky = 0; ky < 5; ++ky)
                    #pragma unroll
                    for (int kx = 0; kx < 5; ++kx)
                        c2 += W2[(4+c)*25 + ky*5 + kx] *
                              p[c*HW + (((h+ky+6)&7)<<5) + ((w+kx+30)&31)];
            }
            ws[OFF_LPANO + pb*HW + tid] = wf0*c1 + wf1*c2;
            return;
        }

        const int ob = pb - B*NN;
        if (ob < B*4) {                       // ---- overhead stats
            const int t = ob*256 + tid;       // t in [0, B*1024)
            const int b = t >> 10, l = t & 1023;
            const float* op = overhead + (size_t)b*CO*LL + l;
            float mx = -INFINITY; double sm = 0.0;
            for (int c = 0; c < CO; ++c) {
                float v = op[(size_t)c*LL];
                mx = fmaxf(mx, v); sm += (double)v;
            }
            ws[OFF_OV(B) + t*2]     = mx;
            ws[OFF_OV(B) + t*2 + 1] = (float)(sm / 64.0);
            return;
        }

        if (tid == 0) {                       // ---- scalar kernel-sums
            double s10=0, s16=0, s17=0, s20=0, s26=0, s27=0;
            for (int i = 0; i < 9;  ++i) { s10 += W1[i]; s16 += W1[54+i];  s17 += W1[63+i]; }
            for (int i = 0; i < 25; ++i) { s20 += W2[i]; s26 += W2[150+i]; s27 += W2[175+i]; }
            ws[OFF_SCAL(B)+0] = (float)(wf0*s10 + wf1*s20);            // Cd
            ws[OFF_SCAL(B)+1] = (float)(wf0*s16 + wf1*s26);            // Com
            ws[OFF_SCAL(B)+2] = (float)(wf0*s17 + wf1*s27);            // Cov
            ws[OFF_SCAL(B)+3] = wf0*b1[0] + wf1*b2[0] + bfp[0];        // Cb
        }
        return;
    }

    if (bid < g1 + gGeo) {                    // ---- geometry: D (f32), idx
        const int t = (bid - g1)*256 + tid;
        if (t >= B*LL*NN) return;
        const int b = t / (LL*NN), r = t % (LL*NN), l = r / NN, n = r % NN;
        const int iy = l >> 5, ix = l & 31;
        const double y0 = (double)bbox[b*4+0], x0 = (double)bbox[b*4+1];
        const double y1 = (double)bbox[b*4+2], x1 = (double)bbox[b*4+3];
        const double cy = y0 + (double)iy * (y1 - y0) / 31.0;
        const double cx = x0 + (double)ix * (x1 - x0) / 31.0;
        const double d0 = (double)locs[(b*NN+n)*2+0] - cy;
        const double d1 = (double)locs[(b*NN+n)*2+1] - cx;
        const double D  = sqrt(d0*d0 + d1*d1);
        double th = atan2(d1, d0);
        const double TWO_PI = 6.283185307179586476925286766559;
        th -= TWO_PI * floor(th / TWO_PI);                 // jnp.mod semantics
        const double deg = th * 57.295779513082320876798154814105;  // 180/pi
        int k = (int)llrint(deg);                          // round-half-even
        int idx = k % 360; if (idx < 0) idx += 360;
        ws[OFF_D(B) + t] = (float)D;
        ((int*)(ws + OFF_IDX(B)))[t] = idx;
        return;
    }

    {                                         // ---- feats f32 -> Bt f16 permute
        const int NG_PER_B = NN*FF*64;
        const int g = (bid - g1 - gGeo)*256 + tid;
        if (g >= B*NG_PER_B) return;
        const int b = g / NG_PER_B;
        const int r = g - b*NG_PER_B;
        const int n = r / (FF*64);
        const int r2 = r % (FF*64);
        const int f = r2 >> 6;
        const int hw0 = (r2 & 63) << 2;
        const float4 v = *(const float4*)(feats + ((size_t)((b*NN + n)*FF + f))*HW + hw0);
        f16x4 h;
        h[0] = (_Float16)v.x; h[1] = (_Float16)v.y;
        h[2] = (_Float16)v.z; h[3] = (_Float16)v.w;
        _Float16* bt = (_Float16*)(ws + OFF_BT(B));
        *(f16x4*)(bt + ((size_t)(b*FF + f))*KK + n*HW + hw0) = h;
    }
}

// ---------------------------------------------------------------------------
// kB: per-(b,l) softmax STATS (mx, inv) + base[b,l,n]. No big write.
// ---------------------------------------------------------------------------
__global__ __launch_bounds__(256)
void kB_stats(float* __restrict__ ws, int B)
{
    const int bid = blockIdx.x, tid = threadIdx.x;
    const int b = bid / LL;
    const float* Lray  = ws;
    const float* Lpano = ws + OFF_LPANO;

    __shared__ float sb[NN];
    __shared__ int   si[NN];
    __shared__ float sred[8];
    if (tid < NN) {
        const float Dv = ws[OFF_D(B) + (size_t)bid*NN + tid];
        const int   ix = ((const int*)(ws + OFF_IDX(B)))[(size_t)bid*NN + tid];
        const float Cd  = ws[OFF_SCAL(B)+0], Com = ws[OFF_SCAL(B)+1];
        const float Cov = ws[OFF_SCAL(B)+2], Cb  = ws[OFF_SCAL(B)+3];
        const float bv = Cd*Dv + Com*ws[OFF_OV(B)+bid*2]
                       + Cov*ws[OFF_OV(B)+bid*2+1] + Cb;
        sb[tid] = bv; si[tid] = ix;
        ws[OFF_BASE2(B) + (size_t)bid*NN + tid] = bv;
    }
    __syncthreads();

    float lg[NN];
    float mx = -INFINITY;
    #pragma unroll
    for (int n = 0; n < NN; ++n) {
        lg[n] = sb[n] + Lray[si[n]*HW + tid] + Lpano[(b*NN+n)*HW + tid];
        mx = fmaxf(mx, lg[n]);
    }
    #pragma unroll
    for (int o = 32; o > 0; o >>= 1) mx = fmaxf(mx, __shfl_xor(mx, o, 64));
    if ((tid & 63) == 0) sred[tid >> 6] = mx;
    __syncthreads();
    mx = fmaxf(fmaxf(sred[0], sred[1]), fmaxf(sred[2], sred[3]));

    float sm = 0.f;
    #pragma unroll
    for (int n = 0; n < NN; ++n) sm += expf(lg[n] - mx);
    #pragma unroll
    for (int o = 32; o > 0; o >>= 1) sm += __shfl_xor(sm, o, 64);
    if ((tid & 63) == 0) sred[4 + (tid >> 6)] = sm;
    __syncthreads();
    if (tid == 0) {
        ws[OFF_MX(B)  + bid] = mx;
        ws[OFF_INV(B) + bid] = 1.0f / (sred[4] + sred[5] + sred[6] + sred[7]);
    }
}

// ---------------------------------------------------------------------------
// kC: fused weight-gen + split-K f16 MFMA GEMM.
//     Regenerates the 640-k weight chunk from (base,Lray,Lpano,mx,inv),
//     writes f32 weights to d_out (only write), feeds f16 MFMA via swizzled LDS.
// ---------------------------------------------------------------------------
__global__ __launch_bounds__(256)
void kC_gemm(const float* __restrict__ ws, float* __restrict__ wout,
             float* __restrict__ cp, int B)
{
    __shared__ __align__(16) _Float16 As[BM*BK];     //  4 KB, swizzled
    __shared__ __align__(16) _Float16 Bs[FF*BK];     // 16 KB, swizzled
    __shared__ float smx[BM], sinv[BM], sbase[BM*3];
    __shared__ int   sidx2[BM*3];

    const int x = blockIdx.x;
    const int ks = x & 7, mb = (x >> 3) & 31, b = x >> 8;
    const int l0 = mb * BM;
    const int kc0 = ks * KC;
    const int n0 = kc0 >> 8;
    const int bl0 = b*LL + l0;
    const int tid = threadIdx.x;
    const int wid = tid >> 6, lane = tid & 63, lr = lane & 15, lk = lane >> 4;

    if (tid < BM) {
        smx[tid]  = ws[OFF_MX(B)  + bl0 + tid];
        sinv[tid] = ws[OFF_INV(B) + bl0 + tid];
    } else if (tid >= 64 && tid < 64 + BM*3) {
        const int t = tid - 64;
        const int row = t/3, jj = t - row*3, n = n0 + jj;
        float bv = 0.f; int ix = 0;
        if (n < NN) {
            bv = ws[OFF_BASE2(B) + (size_t)(bl0 + row)*NN + n];
            ix = ((const int*)(ws + OFF_IDX(B)))[(size_t)(bl0 + row)*NN + n];
        }
        sbase[t] = bv; sidx2[t] = ix;
    }

    const _Float16* Btb = (const _Float16*)(ws + OFF_BT(B)) + (size_t)b*FF*KK;

    f32x4 acc[2][2] = {};

    // fragment LDS byte addresses (swizzle: byte ^= (row&7)<<4 within row)
    int aoff[2][2], boff[2][2];
    #pragma unroll
    for (int m = 0; m < 2; ++m)
        #pragma unroll
        for (int kk = 0; kk < 2; ++kk) {
            const int row = m*16 + lr;
            aoff[m][kk] = row*128 + ((kk*64 + lk*16) ^ ((row & 7) << 4));
        }
    #pragma unroll
    for (int n = 0; n < 2; ++n)
        #pragma unroll
        for (int kk = 0; kk < 2; ++kk) {
            const int row = wid*32 + n*16 + lr;
            boff[n][kk] = row*128 + ((kk*64 + lk*16) ^ ((row & 7) << 4));
        }

    const int arow = tid >> 3, ac8 = tid & 7;
    const int adst = arow*128 + ((ac8*16) ^ ((arow & 7) << 4));

    char* AsB = (char*)As;
    char* BsB = (char*)Bs;

    __syncthreads();

    for (int s = 0; s < KC/BK; ++s) {
        const int kc = kc0 + s*BK;
        const int n = kc >> 8, jj = n - n0;
        // ---- A stage: regenerate 32x64 weights, write f32 out, f16 -> LDS
        {
            const int hwt = (kc & 255) + ac8*8;
            const float* lrp = ws + (size_t)sidx2[arow*3 + jj]*HW + hwt;
            const float* lpp = ws + OFF_LPANO + (size_t)(b*NN + n)*HW + hwt;
            const float bb = sbase[arow*3 + jj];
            const float m  = smx[arow];
            const float iv = sinv[arow];
            const float4 r0 = *(const float4*)lrp;
            const float4 r1 = *(const float4*)(lrp + 4);
            const float4 p0 = *(const float4*)lpp;
            const float4 p1 = *(const float4*)(lpp + 4);
            float w0 = expf(((bb + r0.x) + p0.x) - m) * iv;
            float w1 = expf(((bb + r0.y) + p0.y) - m) * iv;
            float w2 = expf(((bb + r0.z) + p0.z) - m) * iv;
            float w3 = expf(((bb + r0.w) + p0.w) - m) * iv;
            float w4 = expf(((bb + r1.x) + p1.x) - m) * iv;
            float w5 = expf(((bb + r1.y) + p1.y) - m) * iv;
            float w6 = expf(((bb + r1.z) + p1.z) - m) * iv;
            float w7 = expf(((bb + r1.w) + p1.w) - m) * iv;
            float* wp = wout + (size_t)(bl0 + arow)*KK + kc + ac8*8;
            const float4 o0 = {w0, w1, w2, w3};
            const float4 o1 = {w4, w5, w6, w7};
            *(float4*)wp = o0;
            *(float4*)(wp + 4) = o1;
            f16x8 h;
            h[0] = (_Float16)w0; h[1] = (_Float16)w1;
            h[2] = (_Float16)w2; h[3] = (_Float16)w3;
            h[4] = (_Float16)w4; h[5] = (_Float16)w5;
            h[6] = (_Float16)w6; h[7] = (_Float16)w7;
            *(f16x8*)(AsB + adst) = h;
        }
        // ---- B stage: 128x64 f16, swizzled
        #pragma unroll
        for (int c = 0; c < 4; ++c) {
            const int e = c*256 + tid;
            const int row = e >> 3, c8 = e & 7;
            const f16x8 h = *(const f16x8*)(Btb + (size_t)row*KK + kc + c8*8);
            const int dst = row*128 + ((c8*16) ^ ((row & 7) << 4));
            *(f16x8*)(BsB + dst) = h;
        }
        __syncthreads();
        // ---- compute: 8 MFMA
        #pragma unroll
        for (int kk = 0; kk < 2; ++kk) {
            const f16x8 a0 = *(const f16x8*)(AsB + aoff[0][kk]);
            const f16x8 a1 = *(const f16x8*)(AsB + aoff[1][kk]);
            const f16x8 b0 = *(const f16x8*)(BsB + boff[0][kk]);
            const f16x8 b1 = *(const f16x8*)(BsB + boff[1][kk]);
            acc[0][0] = __builtin_amdgcn_mfma_f32_16x16x32_f16(a0, b0, acc[0][0], 0, 0, 0);
            acc[0][1] = __builtin_amdgcn_mfma_f32_16x16x32_f16(a0, b1, acc[0][1], 0, 0, 0);
            acc[1][0] = __builtin_amdgcn_mfma_f32_16x16x32_f16(a1, b0, acc[1][0], 0, 0, 0);
            acc[1][1] = __builtin_amdgcn_mfma_f32_16x16x32_f16(a1, b1, acc[1][1], 0, 0, 0);
        }
        __syncthreads();
    }

    // ---- write partials: Cp[ks][b*LL + l][f]
    float* cpb = cp + ((size_t)ks*B*LL + (size_t)bl0)*FF;
    #pragma unroll
    for (int m = 0; m < 2; ++m)
        #pragma unroll
        for (int n = 0; n < 2; ++n) {
            const int col = wid*32 + n*16 + lr;
            #pragma unroll
            for (int r = 0; r < 4; ++r) {
                const int row = m*16 + lk*4 + r;
                cpb[(size_t)row*FF + col] = acc[m][n][r];
            }
        }
}

// ---------------------------------------------------------------------------
// kD: reduce split-K partials -> grid_feats
// ---------------------------------------------------------------------------
__global__ __launch_bounds__(256)
void kD_reduce(const float* __restrict__ cp, float* __restrict__ gout, int B)
{
    const size_t total = (size_t)B*LL*FF;
    const size_t i = ((size_t)blockIdx.x*256 + threadIdx.x)*4;
    if (i >= total) return;
    float4 s = {0.f, 0.f, 0.f, 0.f};
    #pragma unroll
    for (int ks = 0; ks < KS; ++ks) {
        const float4 v = *(const float4*)(cp + ks*total + i);
        s.x += v.x; s.y += v.y; s.z += v.z; s.w += v.w;
    }
    *(float4*)(gout + i) = s;
}

// ---------------------------------------------------------------------------
extern "C" void kernel_launch(void* const* d_in, const int* in_sizes, int n_in,
                              void* d_out, int out_size, void* d_ws, size_t ws_size,
                              hipStream_t stream)
{
    const float* bbox  = (const float*)d_in[0];
    const float* locs  = (const float*)d_in[1];
    const float* feats = (const float*)d_in[2];
    const float* over  = (const float*)d_in[3];
    const float* rays  = (const float*)d_in[4];
    const float* W1    = (const float*)d_in[5];
    const float* b1    = (const float*)d_in[6];
    const float* W2    = (const float*)d_in[7];
    const float* b2    = (const float*)d_in[8];
    const float* Wf    = (const float*)d_in[9];
    const float* bfp   = (const float*)d_in[10];
    const int B = in_sizes[0] / 4;
    float* ws  = (float*)d_ws;
    float* out = (float*)d_out;
    float* wout = out + (size_t)B*LL*FF;           // f32 weight output region
    float* cp   = ws + OFF_CP(B);

    const int g1   = AA + B*NN + B*4 + 1;
    const int gGeo = (B*LL*NN + 255)/256;
    const int gBt  = (B*NN*FF*64)/256;

    kA_pre<<<dim3(g1 + gGeo + gBt), dim3(256), 0, stream>>>(
        bbox, locs, rays, feats, over, W1, b1, W2, b2, Wf, bfp, ws, B);
    kB_stats<<<dim3(B*LL), dim3(256), 0, stream>>>(ws, B);
    kC_gemm<<<dim3(B*32*KS), dim3(256), 0, stream>>>(ws, wout, cp, B);
    kD_reduce<<<dim3((B*LL*FF/4 + 255)/256), dim3(256), 0, stream>>>(cp, out, B);
}

// Round 4
// 42.254 us; speedup vs baseline: 1.0329x; 1.0329x over previous
//
#include <hip/hip_runtime.h>
#include <hip/hip_fp16.h>
#include <math.h>

#define HH 8
#define WW 32
#define HW 256
#define NN 20
#define FF 128
#define LL 1024
#define AA 360
#define CO 64
#define KK 5120          // NN*HW
#define KS 8             // K splits
#define KC 640           // K per split
#define BM 32            // rows per block in kC
#define BK 64            // K per step

// workspace offsets (in floats)
#define OFF_LPANO      (AA*HW)
#define OFF_OV(B)      (OFF_LPANO + (B)*NN*HW)
#define OFF_SCAL(B)    (OFF_OV(B) + (B)*LL*2)
#define OFF_D(B)       (OFF_SCAL(B) + 8)
#define OFF_IDX(B)     (OFF_D(B) + (B)*LL*NN)
#define OFF_BASE2(B)   (OFF_IDX(B) + (B)*LL*NN)
#define OFF_MX(B)      (OFF_BASE2(B) + (B)*LL*NN)
#define OFF_INV(B)     (OFF_MX(B) + (B)*LL)
#define OFF_BT(B)      (((OFF_INV(B) + (B)*LL + 7)/8)*8)   // f16 Bt2, fragment-major
#define OFF_CP(B)      (OFF_BT(B) + (B)*FF*KK/2)           // f32 partials [KS][B*LL][128]

typedef __attribute__((ext_vector_type(8))) _Float16 f16x8;
typedef __attribute__((ext_vector_type(4))) _Float16 f16x4;
typedef __attribute__((ext_vector_type(4))) float f32x4;

// ---------------------------------------------------------------------------
// kA: fused prologue — tables/stats/scalars; geometry; feats -> Bt2 f16
//     (fragment-major: unit u = ((b*160 + K8/4)*128 + f)*4 + (K8&3), K8=k/8)
// ---------------------------------------------------------------------------
__global__ __launch_bounds__(256)
void kA_pre(const float* __restrict__ bbox, const float* __restrict__ locs,
            const float* __restrict__ rays, const float* __restrict__ feats,
            const float* __restrict__ overhead,
            const float* __restrict__ W1, const float* __restrict__ b1,
            const float* __restrict__ W2, const float* __restrict__ b2,
            const float* __restrict__ Wf, const float* __restrict__ bfp,
            float* __restrict__ ws, int B)
{
    const int bid = blockIdx.x, tid = threadIdx.x;
    const int g1 = AA + B*NN + B*4 + 1;
    const int gGeo = (B*LL*NN + 255)/256;

    if (bid < g1) {
        const float wf0 = Wf[0], wf1 = Wf[1];

        if (bid < AA) {                       // ---- Lray for angle bid
            __shared__ float s[3*HW];
            for (int c = 0; c < 3; ++c) s[c*HW + tid] = rays[(bid*3 + c)*HW + tid];
            __syncthreads();
            const int h = tid >> 5, w = tid & 31;
            float c1 = 0.f, c2 = 0.f;
            #pragma unroll
            for (int c = 0; c < 3; ++c) {
                #pragma unroll
                for (int ky = 0; ky < 3; ++ky)
                    #pragma unroll
                    for (int kx = 0; kx < 3; ++kx)
                        c1 += W1[(1+c)*9 + ky*3 + kx] *
                              s[c*HW + (((h+ky+7)&7)<<5) + ((w+kx+31)&31)];
                #pragma unroll
                for (int ky = 0; ky < 5; ++ky)
                    #pragma unroll
                    for (int kx = 0; kx < 5; ++kx)
                        c2 += W2[(1+c)*25 + ky*5 + kx] *
                              s[c*HW + (((h+ky+6)&7)<<5) + ((w+kx+30)&31)];
            }
            ws[bid*HW + tid] = wf0*c1 + wf1*c2;
            return;
        }

        const int pb = bid - AA;
        if (pb < B*NN) {                      // ---- pano stats + conv -> Lpano
            __shared__ float p[2*HW];
            const float* fp = feats + (size_t)pb * FF * HW + tid;
            float mx = -INFINITY; double sm = 0.0;
            for (int f = 0; f < FF; ++f) {
                float v = fp[(size_t)f * HW];
                mx = fmaxf(mx, v); sm += (double)v;
            }
            p[tid]      = mx;
            p[HW + tid] = (float)(sm / 128.0);
            __syncthreads();
            const int h = tid >> 5, w = tid & 31;
            float c1 = 0.f, c2 = 0.f;
            #pragma unroll
            for (int c = 0; c < 2; ++c) {
                #pragma unroll
                for (int ky = 0; ky < 3; ++ky)
                    #pragma unroll
                    for (int kx = 0; kx < 3; ++kx)
                        c1 += W1[(4+c)*9 + ky*3 + kx] *
                              p[c*HW + (((h+ky+7)&7)<<5) + ((w+kx+31)&31)];
                #pragma unroll
                for (int ky = 0; ky < 5; ++ky)
                    #pragma unroll
                    for (int kx = 0; kx < 5; ++kx)
                        c2 += W2[(4+c)*25 + ky*5 + kx] *
                              p[c*HW + (((h+ky+6)&7)<<5) + ((w+kx+30)&31)];
            }
            ws[OFF_LPANO + pb*HW + tid] = wf0*c1 + wf1*c2;
            return;
        }

        const int ob = pb - B*NN;
        if (ob < B*4) {                       // ---- overhead stats
            const int t = ob*256 + tid;       // t in [0, B*1024)
            const int b = t >> 10, l = t & 1023;
            const float* op = overhead + (size_t)b*CO*LL + l;
            float mx = -INFINITY; double sm = 0.0;
            for (int c = 0; c < CO; ++c) {
                float v = op[(size_t)c*LL];
                mx = fmaxf(mx, v); sm += (double)v;
            }
            ws[OFF_OV(B) + t*2]     = mx;
            ws[OFF_OV(B) + t*2 + 1] = (float)(sm / 64.0);
            return;
        }

        if (tid == 0) {                       // ---- scalar kernel-sums
            double s10=0, s16=0, s17=0, s20=0, s26=0, s27=0;
            for (int i = 0; i < 9;  ++i) { s10 += W1[i]; s16 += W1[54+i];  s17 += W1[63+i]; }
            for (int i = 0; i < 25; ++i) { s20 += W2[i]; s26 += W2[150+i]; s27 += W2[175+i]; }
            ws[OFF_SCAL(B)+0] = (float)(wf0*s10 + wf1*s20);            // Cd
            ws[OFF_SCAL(B)+1] = (float)(wf0*s16 + wf1*s26);            // Com
            ws[OFF_SCAL(B)+2] = (float)(wf0*s17 + wf1*s27);            // Cov
            ws[OFF_SCAL(B)+3] = wf0*b1[0] + wf1*b2[0] + bfp[0];        // Cb
        }
        return;
    }

    if (bid < g1 + gGeo) {                    // ---- geometry: D (f32), idx
        const int t = (bid - g1)*256 + tid;
        if (t >= B*LL*NN) return;
        const int b = t / (LL*NN), r = t % (LL*NN), l = r / NN, n = r % NN;
        const int iy = l >> 5, ix = l & 31;
        const double y0 = (double)bbox[b*4+0], x0 = (double)bbox[b*4+1];
        const double y1 = (double)bbox[b*4+2], x1 = (double)bbox[b*4+3];
        const double cy = y0 + (double)iy * (y1 - y0) / 31.0;
        const double cx = x0 + (double)ix * (x1 - x0) / 31.0;
        const double d0 = (double)locs[(b*NN+n)*2+0] - cy;
        const double d1 = (double)locs[(b*NN+n)*2+1] - cx;
        const double D  = sqrt(d0*d0 + d1*d1);
        double th = atan2(d1, d0);
        const double TWO_PI = 6.283185307179586476925286766559;
        th -= TWO_PI * floor(th / TWO_PI);                 // jnp.mod semantics
        const double deg = th * 57.295779513082320876798154814105;  // 180/pi
        int k = (int)llrint(deg);                          // round-half-even
        int idx = k % 360; if (idx < 0) idx += 360;
        ws[OFF_D(B) + t] = (float)D;
        ((int*)(ws + OFF_IDX(B)))[t] = idx;
        return;
    }

    {   // ---- feats f32 -> Bt2 f16, fragment-major (linear write: unit == t)
        const int t = (bid - g1 - gGeo)*256 + tid;       // unit index
        if (t >= B*FF*KK/8) return;
        const int r  = t & 3;
        const int f  = (t >> 2) & 127;
        const int q  = (t >> 9) % 160;
        const int b  = (t >> 9) / 160;
        const int K8 = q*4 + r;
        const int n   = K8 >> 5;
        const int hw8 = K8 & 31;
        const float* src = feats + ((size_t)((b*NN + n)*FF + f))*HW + hw8*8;
        const float4 v0 = *(const float4*)src;
        const float4 v1 = *(const float4*)(src + 4);
        f16x8 h;
        h[0] = (_Float16)v0.x; h[1] = (_Float16)v0.y;
        h[2] = (_Float16)v0.z; h[3] = (_Float16)v0.w;
        h[4] = (_Float16)v1.x; h[5] = (_Float16)v1.y;
        h[6] = (_Float16)v1.z; h[7] = (_Float16)v1.w;
        ((f16x8*)(ws + OFF_BT(B)))[t] = h;
    }
}

// ---------------------------------------------------------------------------
// kB: per-(b,l) softmax STATS (mx, inv) + base[b,l,n]. No big write.
// ---------------------------------------------------------------------------
__global__ __launch_bounds__(256)
void kB_stats(float* __restrict__ ws, int B)
{
    const int bid = blockIdx.x, tid = threadIdx.x;
    const int b = bid / LL;
    const float* Lray  = ws;
    const float* Lpano = ws + OFF_LPANO;

    __shared__ float sb[NN];
    __shared__ int   si[NN];
    __shared__ float sred[8];
    if (tid < NN) {
        const float Dv = ws[OFF_D(B) + (size_t)bid*NN + tid];
        const int   ix = ((const int*)(ws + OFF_IDX(B)))[(size_t)bid*NN + tid];
        const float Cd  = ws[OFF_SCAL(B)+0], Com = ws[OFF_SCAL(B)+1];
        const float Cov = ws[OFF_SCAL(B)+2], Cb  = ws[OFF_SCAL(B)+3];
        const float bv = Cd*Dv + Com*ws[OFF_OV(B)+bid*2]
                       + Cov*ws[OFF_OV(B)+bid*2+1] + Cb;
        sb[tid] = bv; si[tid] = ix;
        ws[OFF_BASE2(B) + (size_t)bid*NN + tid] = bv;
    }
    __syncthreads();

    float lg[NN];
    float mx = -INFINITY;
    #pragma unroll
    for (int n = 0; n < NN; ++n) {
        lg[n] = sb[n] + Lray[si[n]*HW + tid] + Lpano[(b*NN+n)*HW + tid];
        mx = fmaxf(mx, lg[n]);
    }
    #pragma unroll
    for (int o = 32; o > 0; o >>= 1) mx = fmaxf(mx, __shfl_xor(mx, o, 64));
    if ((tid & 63) == 0) sred[tid >> 6] = mx;
    __syncthreads();
    mx = fmaxf(fmaxf(sred[0], sred[1]), fmaxf(sred[2], sred[3]));

    float sm = 0.f;
    #pragma unroll
    for (int n = 0; n < NN; ++n) sm += expf(lg[n] - mx);
    #pragma unroll
    for (int o = 32; o > 0; o >>= 1) sm += __shfl_xor(sm, o, 64);
    if ((tid & 63) == 0) sred[4 + (tid >> 6)] = sm;
    __syncthreads();
    if (tid == 0) {
        ws[OFF_MX(B)  + bid] = mx;
        ws[OFF_INV(B) + bid] = 1.0f / (sred[4] + sred[5] + sred[6] + sred[7]);
    }
}

// ---------------------------------------------------------------------------
// kC: fused weight-gen + split-K f16 MFMA GEMM, barrier-free inner loop.
//     Phase 1: regenerate full 32x640 A chunk -> wout (f32) + LDS (f16, swz).
//     Phase 2: 10 steps x 8 MFMA; B-fragments loaded directly global->VGPR
//     from fragment-major Bt2 (no LDS, no barriers).
// ---------------------------------------------------------------------------
__global__ __launch_bounds__(256)
void kC_gemm(const float* __restrict__ ws, float* __restrict__ wout,
             float* __restrict__ cp, int B)
{
    __shared__ __align__(16) _Float16 As[BM*KC];     // 40 KB, swizzled
    __shared__ float smx[BM], sinv[BM], sbase[BM*3];
    __shared__ int   sidx2[BM*3];

    const int x = blockIdx.x;
    const int ks = x & 7, mb = (x >> 3) & 31, b = x >> 8;
    const int l0 = mb * BM;
    const int kc0 = ks * KC;
    const int n0 = kc0 >> 8;
    const int bl0 = b*LL + l0;
    const int tid = threadIdx.x;
    const int wid = tid >> 6, lane = tid & 63, lr = lane & 15, lk = lane >> 4;

    if (tid < BM) {
        smx[tid]  = ws[OFF_MX(B)  + bl0 + tid];
        sinv[tid] = ws[OFF_INV(B) + bl0 + tid];
    } else if (tid >= 64 && tid < 64 + BM*3) {
        const int t = tid - 64;
        const int row = t/3, jj = t - row*3, n = n0 + jj;
        float bv = 0.f; int ix = 0;
        if (n < NN) {
            bv = ws[OFF_BASE2(B) + (size_t)(bl0 + row)*NN + n];
            ix = ((const int*)(ws + OFF_IDX(B)))[(size_t)(bl0 + row)*NN + n];
        }
        sbase[t] = bv; sidx2[t] = ix;
    }
    __syncthreads();

    char* AsB = (char*)As;
    const int arow = tid >> 3, ac8 = tid & 7;
    const float m_  = smx[arow];
    const float iv_ = sinv[arow];

    // ---- Phase 1: regenerate A (32 x 640), write wout once, stage to LDS
    for (int s = 0; s < KC/BK; ++s) {
        const int kc = kc0 + s*BK;
        const int n = kc >> 8, jj = n - n0;
        const int hwt = (kc & 255) + ac8*8;
        const float* lrp = ws + (size_t)sidx2[arow*3 + jj]*HW + hwt;
        const float* lpp = ws + OFF_LPANO + (size_t)(b*NN + n)*HW + hwt;
        const float bb = sbase[arow*3 + jj];
        const float4 r0 = *(const float4*)lrp;
        const float4 r1 = *(const float4*)(lrp + 4);
        const float4 p0 = *(const float4*)lpp;
        const float4 p1 = *(const float4*)(lpp + 4);
        float w0 = expf(((bb + r0.x) + p0.x) - m_) * iv_;
        float w1 = expf(((bb + r0.y) + p0.y) - m_) * iv_;
        float w2 = expf(((bb + r0.z) + p0.z) - m_) * iv_;
        float w3 = expf(((bb + r0.w) + p0.w) - m_) * iv_;
        float w4 = expf(((bb + r1.x) + p1.x) - m_) * iv_;
        float w5 = expf(((bb + r1.y) + p1.y) - m_) * iv_;
        float w6 = expf(((bb + r1.z) + p1.z) - m_) * iv_;
        float w7 = expf(((bb + r1.w) + p1.w) - m_) * iv_;
        float* wp = wout + (size_t)(bl0 + arow)*KK + kc + ac8*8;
        const float4 o0 = {w0, w1, w2, w3};
        const float4 o1 = {w4, w5, w6, w7};
        *(float4*)wp = o0;
        *(float4*)(wp + 4) = o1;
        f16x8 h;
        h[0] = (_Float16)w0; h[1] = (_Float16)w1;
        h[2] = (_Float16)w2; h[3] = (_Float16)w3;
        h[4] = (_Float16)w4; h[5] = (_Float16)w5;
        h[6] = (_Float16)w6; h[7] = (_Float16)w7;
        const int dst = arow*1280 + ((s*128 + ac8*16) ^ ((arow & 7) << 4));
        *(f16x8*)(AsB + dst) = h;
    }
    __syncthreads();

    // ---- Phase 2: barrier-free compute
    const f16x8* Bt2 = (const f16x8*)(ws + OFF_BT(B)) + (size_t)b*FF*KK/8;

    f32x4 acc[2][2] = {};
    for (int s = 0; s < KC/BK; ++s) {
        f16x8 bf[2][2], af[2][2];
        #pragma unroll
        for (int kk = 0; kk < 2; ++kk) {
            const int g = ks*20 + s*2 + kk;
            #pragma unroll
            for (int n = 0; n < 2; ++n)
                bf[n][kk] = Bt2[(size_t)((g*128 + wid*32 + n*16 + lr) << 2) + lk];
        }
        #pragma unroll
        for (int m = 0; m < 2; ++m)
            #pragma unroll
            for (int kk = 0; kk < 2; ++kk) {
                const int row = m*16 + lr;
                const int off = row*1280 + ((s*128 + kk*64 + lk*16) ^ ((lr & 7) << 4));
                af[m][kk] = *(const f16x8*)(AsB + off);
            }
        #pragma unroll
        for (int kk = 0; kk < 2; ++kk) {
            acc[0][0] = __builtin_amdgcn_mfma_f32_16x16x32_f16(af[0][kk], bf[0][kk], acc[0][0], 0, 0, 0);
            acc[0][1] = __builtin_amdgcn_mfma_f32_16x16x32_f16(af[0][kk], bf[1][kk], acc[0][1], 0, 0, 0);
            acc[1][0] = __builtin_amdgcn_mfma_f32_16x16x32_f16(af[1][kk], bf[0][kk], acc[1][0], 0, 0, 0);
            acc[1][1] = __builtin_amdgcn_mfma_f32_16x16x32_f16(af[1][kk], bf[1][kk], acc[1][1], 0, 0, 0);
        }
    }

    // ---- write partials: Cp[ks][b*LL + l][f]
    float* cpb = cp + ((size_t)ks*B*LL + (size_t)bl0)*FF;
    #pragma unroll
    for (int m = 0; m < 2; ++m)
        #pragma unroll
        for (int n = 0; n < 2; ++n) {
            const int col = wid*32 + n*16 + lr;
            #pragma unroll
            for (int r = 0; r < 4; ++r) {
                const int row = m*16 + lk*4 + r;
                cpb[(size_t)row*FF + col] = acc[m][n][r];
            }
        }
}

// ---------------------------------------------------------------------------
// kD: reduce split-K partials -> grid_feats
// ---------------------------------------------------------------------------
__global__ __launch_bounds__(256)
void kD_reduce(const float* __restrict__ cp, float* __restrict__ gout, int B)
{
    const size_t total = (size_t)B*LL*FF;
    const size_t i = ((size_t)blockIdx.x*256 + threadIdx.x)*4;
    if (i >= total) return;
    float4 s = {0.f, 0.f, 0.f, 0.f};
    #pragma unroll
    for (int ks = 0; ks < KS; ++ks) {
        const float4 v = *(const float4*)(cp + ks*total + i);
        s.x += v.x; s.y += v.y; s.z += v.z; s.w += v.w;
    }
    *(float4*)(gout + i) = s;
}

// ---------------------------------------------------------------------------
extern "C" void kernel_launch(void* const* d_in, const int* in_sizes, int n_in,
                              void* d_out, int out_size, void* d_ws, size_t ws_size,
                              hipStream_t stream)
{
    const float* bbox  = (const float*)d_in[0];
    const float* locs  = (const float*)d_in[1];
    const float* feats = (const float*)d_in[2];
    const float* over  = (const float*)d_in[3];
    const float* rays  = (const float*)d_in[4];
    const float* W1    = (const float*)d_in[5];
    const float* b1    = (const float*)d_in[6];
    const float* W2    = (const float*)d_in[7];
    const float* b2    = (const float*)d_in[8];
    const float* Wf    = (const float*)d_in[9];
    const float* bfp   = (const float*)d_in[10];
    const int B = in_sizes[0] / 4;
    float* ws  = (float*)d_ws;
    float* out = (float*)d_out;
    float* wout = out + (size_t)B*LL*FF;           // f32 weight output region
    float* cp   = ws + OFF_CP(B);

    const int g1   = AA + B*NN + B*4 + 1;
    const int gGeo = (B*LL*NN + 255)/256;
    const int gBt  = (B*FF*KK/8 + 255)/256;

    kA_pre<<<dim3(g1 + gGeo + gBt), dim3(256), 0, stream>>>(
        bbox, locs, rays, feats, over, W1, b1, W2, b2, Wf, bfp, ws, B);
    kB_stats<<<dim3(B*LL), dim3(256), 0, stream>>>(ws, B);
    kC_gemm<<<dim3(B*32*KS), dim3(256), 0, stream>>>(ws, wout, cp, B);
    kD_reduce<<<dim3((B*LL*FF/4 + 255)/256), dim3(256), 0, stream>>>(cp, out, B);
}